// Round 21
// baseline (255.415 us; speedup 1.0000x reference)
//
#include <hip/hip_runtime.h>
#include <hip/hip_cooperative_groups.h>
#include <math.h>

namespace cg = cooperative_groups;

#define H_ 128
#define W_ 128
#define B_ 8
#define C_ 64
#define HW_ (H_*W_)
#define PW 130            // padded width/height (halo 1)

typedef _Float16 half8 __attribute__((ext_vector_type(8)));
typedef _Float16 half4t __attribute__((ext_vector_type(4)));
typedef float f32x4 __attribute__((ext_vector_type(4)));

__device__ __forceinline__ int clampi(int v, int lo, int hi) {
    return v < lo ? lo : (v > hi ? hi : v);
}

// async global->LDS 16B (linear dest: wave-uniform base + lane*16)
__device__ __forceinline__ void stage16(const _Float16* g, _Float16* l) {
    __builtin_amdgcn_global_load_lds(
        (const __attribute__((address_space(1))) unsigned int*)g,
        (__attribute__((address_space(3))) unsigned int*)l, 16, 0, 0);
}

// ---- conv3x3 + bias + relu phase: 16 waves, 4 rows x 4 xh-groups of 32 px ----
__device__ __forceinline__ void conv_phase(
    const _Float16* __restrict__ in, const _Float16* __restrict__ wpk,
    const float* __restrict__ bias, _Float16* __restrict__ outp,
    _Float16* Ash, _Float16* Tile, int blk, int tid) {
    const int wv = tid >> 6, l = tid & 63;
    const int l15 = l & 15, lg = l >> 4;
    const int b  = blk & 7;
    const int R  = (blk >> 3) * 4;
    const int rowi = wv >> 2;
    const int xh = (wv & 3) * 32;

    f32x4 acc[4][2];
#pragma unroll
    for (int i = 0; i < 4; ++i)
#pragma unroll
        for (int j = 0; j < 2; ++j) acc[i][j] = (f32x4){0.f, 0.f, 0.f, 0.f};

    half8 bf0[2], bf1[2];

#define LOADB(BF, KK)                                                          \
    {                                                                          \
        _Pragma("unroll") for (int nf = 0; nf < 2; ++nf)                       \
            BF[nf] = *(const half8*)(Tile + (size_t)(((rowi + (KK) / 3) * 4 + lg) \
                          * 130 + xh + (KK) % 3 + nf * 16 + l15) * 8);         \
    }
#define MM(BF, KK)                                                             \
    {                                                                          \
        half8 af_[4];                                                          \
        _Pragma("unroll") for (int mf = 0; mf < 4; ++mf)                       \
            af_[mf] = *(const half8*)(Ash + (size_t)(((KK) * 4 + mf) * 64 + l) * 8); \
        _Pragma("unroll") for (int mf = 0; mf < 4; ++mf)                       \
            _Pragma("unroll") for (int nf = 0; nf < 2; ++nf)                   \
                acc[mf][nf] = __builtin_amdgcn_mfma_f32_16x16x32_f16(          \
                    af_[mf], BF[nf], acc[mf][nf], 0, 0, 0);                    \
    }

#pragma unroll
    for (int ch = 0; ch < 2; ++ch) {
        __syncthreads();   // previous phase's LDS readers done
#pragma unroll
        for (int i = 0; i < 6; ++i) {
            int idx = i * 1024 + tid;
            if (idx < 2304) {
                stage16(wpk + (size_t)ch * 18432 + (size_t)idx * 8,
                        Ash + (size_t)idx * 8);
            } else if (idx < 5424) {
                int t   = idx - 2304;
                int dy  = t / 520;
                int rem = t - dy * 520;
                int pl  = rem / 130;
                int col = rem - pl * 130;
                stage16(in + ((size_t)((b * PW + R + dy) * PW) + col) * C_
                            + ch * 32 + pl * 8,
                        Tile + (size_t)t * 8);
            }
        }
        __syncthreads();   // drains all gload_lds

        LOADB(bf0, 0);
        LOADB(bf1, 1); MM(bf0, 0);
        LOADB(bf0, 2); MM(bf1, 1);
        LOADB(bf1, 3); MM(bf0, 2);
        LOADB(bf0, 4); MM(bf1, 3);
        LOADB(bf1, 5); MM(bf0, 4);
        LOADB(bf0, 6); MM(bf1, 5);
        LOADB(bf1, 7); MM(bf0, 6);
        LOADB(bf0, 8); MM(bf1, 7);
                       MM(bf0, 8);
    }
#undef LOADB
#undef MM

    _Float16* ob = outp + ((size_t)((b * PW + R + rowi + 1) * PW) + xh + 1) * C_;
#pragma unroll
    for (int mf = 0; mf < 4; ++mf) {
        const int co = mf * 16 + lg * 4;
        const float b0 = bias[co], b1 = bias[co + 1], b2 = bias[co + 2], b3 = bias[co + 3];
#pragma unroll
        for (int nf = 0; nf < 2; ++nf) {
            f32x4 v = acc[mf][nf];
            half4t h;
            h[0] = (_Float16)fmaxf(v[0] + b0, 0.f);
            h[1] = (_Float16)fmaxf(v[1] + b1, 0.f);
            h[2] = (_Float16)fmaxf(v[2] + b2, 0.f);
            h[3] = (_Float16)fmaxf(v[3] + b3, 0.f);
            *(half4t*)(ob + (nf * 16 + l15) * C_ + co) = h;
        }
    }
    __syncthreads();   // all LDS readers done before next phase overwrites
}

// ---- deform phase: 16 waves = 4 rows x 4 xh-groups of 32px (R14 logic) ----
__device__ __forceinline__ void deform_phase(
    const _Float16* __restrict__ hin, const float* __restrict__ off,
    const _Float16* __restrict__ wpk, const float* __restrict__ bias,
    float* __restrict__ out,
    _Float16* Ash, _Float16* Win, _Float16* OffS, int blk, int tid) {
    const int wv = tid >> 6, l = tid & 63;
    const int l15 = l & 15, lg = l >> 4;
    const int b  = blk & 7;
    const int R  = (blk >> 3) * 4;
    const int r  = R + (wv >> 2);
    const int xh = (wv & 3) * 32;

    const _Float16* hb = hin + (size_t)b * PW * PW * C_;
    const float* offp = off + (size_t)b * 9 * HW_ * 2;

    // stage offsets once: 9 taps x 4 rows x 128 px float2 = 2304 chunks
#pragma unroll
    for (int i = 0; i < 3; ++i) {
        int idx = i * 1024 + tid;
        if (idx < 2304) {
            int kk = idx >> 8, rowi = (idx >> 6) & 3, c = idx & 63;
            const _Float16* g = (const _Float16*)(offp
                + ((size_t)kk * HW_ + (R + rowi) * W_) * 2) + c * 8;
            stage16(g, OffS + (size_t)idx * 8);
        }
    }

    f32x4 acc[4][2];
#pragma unroll
    for (int i = 0; i < 4; ++i)
#pragma unroll
        for (int j = 0; j < 2; ++j) acc[i][j] = (f32x4){0.f, 0.f, 0.f, 0.f};

    half8 bf[2];

#define GATHB(KK, CH) do {                                                     \
    _Pragma("unroll") for (int nf = 0; nf < 2; ++nf) {                         \
        const int pxl = xh + nf * 16 + l15;                                    \
        float2 o2 = *(const float2*)(OffS +                                    \
            (size_t)((((KK) * 4 + (r - R)) << 7) + pxl) * 4);                  \
        float py = (float)(r + (KK) / 3 - 1) + o2.x;                           \
        float px = (float)(pxl + (KK) % 3 - 1) + o2.y;                         \
        float fy0 = floorf(py), fx0 = floorf(px);                              \
        float fy = py - fy0, fx = px - fx0;                                    \
        int iy0 = (int)fy0, ix0 = (int)fx0;                                    \
        int cy0 = clampi(iy0, -1, 128), cy1 = clampi(iy0 + 1, -1, 128);        \
        int px0 = clampi(ix0, -1, 128) + 1, px1 = clampi(ix0 + 1, -1, 128) + 1;\
        _Float16 w00 = (_Float16)((1.f - fy) * (1.f - fx));                    \
        _Float16 w01 = (_Float16)((1.f - fy) * fx);                            \
        _Float16 w10 = (_Float16)(fy * (1.f - fx));                            \
        _Float16 w11 = (_Float16)(fy * fx);                                    \
        half8 c0, c1, c2, c3;                                                  \
        int s0 = cy0 + 2 - R, s1 = cy1 + 2 - R;                                \
        if (__all((s0 >= 0) & (s1 <= 7))) {                                    \
            const _Float16* w0 = Win + (size_t)(s0 * 130) * 40 + lg * 8;       \
            const _Float16* w1 = Win + (size_t)(s1 * 130) * 40 + lg * 8;       \
            c0 = *(const half8*)(w0 + px0 * 40);                               \
            c1 = *(const half8*)(w0 + px1 * 40);                               \
            c2 = *(const half8*)(w1 + px0 * 40);                               \
            c3 = *(const half8*)(w1 + px1 * 40);                               \
        } else {                                                               \
            const _Float16* g0 = hb + (size_t)((cy0 + 1) * PW) * C_ + (CH) * 32 + lg * 8; \
            const _Float16* g1 = hb + (size_t)((cy1 + 1) * PW) * C_ + (CH) * 32 + lg * 8; \
            c0 = *(const half8*)(g0 + px0 * C_);                               \
            c1 = *(const half8*)(g0 + px1 * C_);                               \
            c2 = *(const half8*)(g1 + px0 * C_);                               \
            c3 = *(const half8*)(g1 + px1 * C_);                               \
        }                                                                      \
        bf[nf] = (c0 * w00 + c1 * w01) + (c2 * w10 + c3 * w11);                \
    }                                                                          \
} while (0)
#define MMT(KK) do {                                                           \
    half8 af0 = *(const half8*)(Ash + (size_t)(((KK) * 4 + 0) * 64 + l) * 8);  \
    half8 af1 = *(const half8*)(Ash + (size_t)(((KK) * 4 + 1) * 64 + l) * 8);  \
    half8 af2 = *(const half8*)(Ash + (size_t)(((KK) * 4 + 2) * 64 + l) * 8);  \
    half8 af3 = *(const half8*)(Ash + (size_t)(((KK) * 4 + 3) * 64 + l) * 8);  \
    _Pragma("unroll") for (int nf = 0; nf < 2; ++nf) {                         \
        acc[0][nf] = __builtin_amdgcn_mfma_f32_16x16x32_f16(af0, bf[nf], acc[0][nf], 0, 0, 0); \
        acc[1][nf] = __builtin_amdgcn_mfma_f32_16x16x32_f16(af1, bf[nf], acc[1][nf], 0, 0, 0); \
        acc[2][nf] = __builtin_amdgcn_mfma_f32_16x16x32_f16(af2, bf[nf], acc[2][nf], 0, 0, 0); \
        acc[3][nf] = __builtin_amdgcn_mfma_f32_16x16x32_f16(af3, bf[nf], acc[3][nf], 0, 0, 0); \
    }                                                                          \
} while (0)

#pragma unroll
    for (int ch = 0; ch < 2; ++ch) {
        __syncthreads();   // previous half's LDS readers done (drains OffS stage too)
#pragma unroll
        for (int i = 0; i < 3; ++i) {
            int idx = i * 1024 + tid;
            if (idx < 2304)
                stage16(wpk + (size_t)ch * 18432 + (size_t)idx * 8,
                        Ash + (size_t)idx * 8);
        }
#pragma unroll
        for (int i = 0; i < 6; ++i) {
            int idx = i * 1024 + tid;
            if (idx < 5200) {
                int s   = idx / 650;
                int rem = idx - s * 650;
                int c   = rem / 5;
                int q   = rem - c * 5;
                int prow = clampi(R - 1 + s, 0, 129);
                stage16(hb + ((size_t)(prow * PW) + c) * C_ + ch * 32 + (q < 4 ? q : 3) * 8,
                        Win + (size_t)idx * 8);
            }
        }
        __syncthreads();   // drains all gload_lds

        GATHB(0, ch); MMT(0);
        GATHB(1, ch); MMT(1);
        GATHB(2, ch); MMT(2);
        GATHB(3, ch); MMT(3);
        GATHB(4, ch); MMT(4);
        GATHB(5, ch); MMT(5);
        GATHB(6, ch); MMT(6);
        GATHB(7, ch); MMT(7);
        GATHB(8, ch); MMT(8);
    }
#undef GATHB
#undef MMT

    // ---- transposed epilogue: 4 passes of 16 couts through Win, full-line stores
    float* WF = (float*)Win;
    float* obase = out + (size_t)b * C_ * HW_;
#pragma unroll
    for (int p = 0; p < 4; ++p) {
        __syncthreads();   // Win free (taps done / previous pass read)
#pragma unroll
        for (int nf = 0; nf < 2; ++nf) {
            f32x4 v = acc[p][nf];
#pragma unroll
            for (int rr = 0; rr < 4; ++rr) {
                int co16 = lg * 4 + rr;
                WF[co16 * 512 + (r - R) * 128 + xh + nf * 16 + l15]
                    = v[rr] + bias[p * 16 + co16];
            }
        }
        __syncthreads();
#pragma unroll
        for (int i = 0; i < 2; ++i) {
            int g4   = i * 1024 + tid;
            int co16 = g4 >> 7;
            int q    = g4 & 127;
            int rr2  = q >> 5;
            int px4  = q & 31;
            f32x4 v = *(const f32x4*)&WF[g4 * 4];
            *(f32x4*)(obase + (size_t)(p * 16 + co16) * HW_ + (R + rr2) * W_ + px4 * 4) = v;
        }
    }
}

// ================= FUSED COOPERATIVE KERNEL =================
// grid = 256 blocks x 1024 thr (1 block/CU). Phases separated by grid.sync():
// PREP -> conv1 -> conv2 -> conv3 -> deform.
__global__ __launch_bounds__(1024, 1)
void fused_kernel(const float* __restrict__ x,  const float* __restrict__ of,
                  const float* __restrict__ w1, const float* __restrict__ w2,
                  const float* __restrict__ w3, const float* __restrict__ wd,
                  const float* __restrict__ wof, const float* __restrict__ bof,
                  const float* __restrict__ b1, const float* __restrict__ b2,
                  const float* __restrict__ b3, const float* __restrict__ bd,
                  float* __restrict__ out, float* __restrict__ offb,
                  _Float16* __restrict__ wpA, _Float16* __restrict__ xp,
                  _Float16* __restrict__ hA, _Float16* __restrict__ hB) {
    cg::grid_group grid = cg::this_grid();
    __shared__ long long Ubuf[19616];          // 156928 B union
    _Float16* U = (_Float16*)Ubuf;
    const int blk = blockIdx.x, tid = threadIdx.x;

    // ---------------- PREP ----------------
    {
        int T = blk * 1024 + tid;
        if (T < 131072) {                       // offconv: px T
            int bi = T >> 14, p = T & 16383;
            float a0 = of[(bi * 2 + 0) * HW_ + p];
            float a1 = of[(bi * 2 + 1) * HW_ + p];
#pragma unroll
            for (int kk = 0; kk < 9; ++kk) {
                float dy = bof[2 * kk]     + wof[(2 * kk) * 2] * a0     + wof[(2 * kk) * 2 + 1] * a1;
                float dx = bof[2 * kk + 1] + wof[(2 * kk + 1) * 2] * a0 + wof[(2 * kk + 1) * 2 + 1] * a1;
                float2 v; v.x = dy; v.y = dx;
                *(float2*)(offb + ((size_t)(bi * 9 + kk) * HW_ + p) * 2) = v;
            }
        } else if (T < 149504) {                // wpack: item T-131072
            int u4 = T - 131072;
            int set = u4 / 4608;
            int u   = u4 - set * 4608;
            const float* w = (set == 0) ? w1 : (set == 1) ? w2 : (set == 2) ? w3 : wd;
            int l  = u & 63;
            int mf = (u >> 6) & 3;
            int ch = (u >> 8) & 1;
            int kk = u >> 9;
            int co   = mf * 16 + (l & 15);
            int cin0 = ch * 32 + (l >> 4) * 8;
            half8 v;
#pragma unroll
            for (int j = 0; j < 8; ++j)
                v[j] = (_Float16)w[((co * C_) + cin0 + j) * 9 + kk];
            *(half8*)(wpA + (size_t)set * 36864
                          + (size_t)(((ch * 9 + kk) * 4 + mf) * 64 + l) * 8) = v;
        } else if (T < 161888) {                // zpad: item T-149504 (3 arrays)
            int u0 = T - 149504;
            int which = u0 / (B_ * 516);
            int u = u0 - which * (B_ * 516);
            _Float16* o = (which == 0) ? xp : (which == 1) ? hA : hB;
            int b = u / 516, i = u % 516;
            int yp, xpx;
            if (i < 260) { yp = (i < 130) ? 0 : (PW - 1); xpx = i % 130; }
            else {
                int j = i - 260;
                if (j < 128) { xpx = 0; yp = j + 1; }
                else         { xpx = PW - 1; yp = j - 128 + 1; }
            }
            _Float16* dst = o + ((size_t)(b * PW + yp) * PW + xpx) * C_;
            half8 z = (half8)(_Float16)0.f;
#pragma unroll
            for (int c8 = 0; c8 < 8; ++c8) *(half8*)(dst + c8 * 8) = z;
        }
        // xpad: ALL blocks; group g = tid>>8 handles row task blk*4+g
        {
            float* ldsx = (float*)Ubuf + (size_t)(tid >> 8) * (64 * 129);
            int rt = blk * 4 + (tid >> 8);
            int b = rt & 7, y = rt >> 3;
            int t2 = tid & 255;
            const int xr = t2 & 127, cr = t2 >> 7;
            const float* src = x + (size_t)b * C_ * HW_ + y * W_;
#pragma unroll
            for (int i = 0; i < 32; ++i) {
                int c = i * 2 + cr;
                ldsx[c * 129 + xr] = src[(size_t)c * HW_ + xr];
            }
            __syncthreads();
            const int px = t2 & 127, hf = t2 >> 7;
            _Float16* dst = xp + ((size_t)((b * PW + y + 1) * PW) + px + 1) * C_ + hf * 32;
#pragma unroll
            for (int q = 0; q < 4; ++q) {
                half8 v;
#pragma unroll
                for (int j = 0; j < 8; ++j)
                    v[j] = (_Float16)ldsx[(hf * 32 + q * 8 + j) * 129 + px];
                *(half8*)(dst + q * 8) = v;
            }
        }
    }
    grid.sync();

    // LDS aliases
    _Float16* AshC  = U;                        // 36864 B
    _Float16* TileC = U + 18432;                // 49920 B  (18432 halves offset)
    _Float16* AshD  = U;                        // 36864 B
    _Float16* WinD  = U + 18432;                // 83200 B
    _Float16* OffSD = U + 18432 + 41600;        // 36864 B  (total 156928)

    conv_phase(xp, wpA,             b1, hA, AshC, TileC, blk, tid);
    grid.sync();
    conv_phase(hA, wpA + 36864,     b2, hB, AshC, TileC, blk, tid);
    grid.sync();
    conv_phase(hB, wpA + 2 * 36864, b3, hA, AshC, TileC, blk, tid);
    grid.sync();
    deform_phase(hA, offb, wpA + 3 * 36864, bd, out, AshD, WinD, OffSD, blk, tid);
}

extern "C" void kernel_launch(void* const* d_in, const int* in_sizes, int n_in,
                              void* d_out, int out_size, void* d_ws, size_t ws_size,
                              hipStream_t stream) {
    const float* x     = (const float*)d_in[0];
    const float* of    = (const float*)d_in[1];
    const float* w1    = (const float*)d_in[2];
    const float* b1    = (const float*)d_in[3];
    const float* w2    = (const float*)d_in[4];
    const float* b2    = (const float*)d_in[5];
    const float* w3    = (const float*)d_in[6];
    const float* b3    = (const float*)d_in[7];
    const float* w_off = (const float*)d_in[8];
    const float* b_off = (const float*)d_in[9];
    const float* w_d   = (const float*)d_in[10];
    const float* b_d   = (const float*)d_in[11];
    float* out = (float*)d_out;

    char* base = (char*)d_ws;
    float*     offb = (float*)base;                           // 9.44 MB
    char* p = base + (size_t)B_ * 18 * HW_ * 4;
    _Float16* wpA = (_Float16*)p;                             // 4 contiguous sets
    p += 4 * 36864 * 2;
    _Float16* xp = (_Float16*)p; p += (size_t)B_ * PW * PW * C_ * 2;  // 17.3 MB
    _Float16* hA = (_Float16*)p; p += (size_t)B_ * PW * PW * C_ * 2;
    _Float16* hB = (_Float16*)p;

    void* args[] = {
        (void*)&x, (void*)&of, (void*)&w1, (void*)&w2, (void*)&w3, (void*)&w_d,
        (void*)&w_off, (void*)&b_off, (void*)&b1, (void*)&b2, (void*)&b3,
        (void*)&b_d, (void*)&out, (void*)&offb, (void*)&wpA, (void*)&xp,
        (void*)&hA, (void*)&hB
    };
    hipLaunchCooperativeKernel((void*)fused_kernel, dim3(256), dim3(1024),
                               args, 0, stream);
}

// Round 22
// 103.595 us; speedup vs baseline: 2.4655x; 2.4655x over previous
//
#include <hip/hip_runtime.h>
#include <math.h>

#define H_ 128
#define W_ 128
#define B_ 8
#define C_ 64
#define HW_ (H_*W_)
#define PW 130            // padded width/height (halo 1)

typedef _Float16 half8 __attribute__((ext_vector_type(8)));
typedef _Float16 half4t __attribute__((ext_vector_type(4)));
typedef float f32x4 __attribute__((ext_vector_type(4)));

__device__ __forceinline__ int clampi(int v, int lo, int hi) {
    return v < lo ? lo : (v > hi ? hi : v);
}

// async global->LDS 16B (linear dest: wave-uniform base + lane*16)
__device__ __forceinline__ void stage16(const _Float16* g, _Float16* l) {
    __builtin_amdgcn_global_load_lds(
        (const __attribute__((address_space(1))) unsigned int*)g,
        (__attribute__((address_space(3))) unsigned int*)l, 16, 0, 0);
}

// ======== FUSED PREP: wpack | zpad x3 | xpad | offconv in one launch ========
// grid segments: [0,72) wpack, [72,121) zpad, [121,1145) xpad, [1145,1657) offconv
__global__ __launch_bounds__(256, 4)
void prep_kernel(const float* __restrict__ w1, const float* __restrict__ w2,
                 const float* __restrict__ w3, const float* __restrict__ wd,
                 _Float16* __restrict__ wp,
                 _Float16* __restrict__ z0, _Float16* __restrict__ z1,
                 _Float16* __restrict__ z2,
                 const float* __restrict__ x,  _Float16* __restrict__ xp,
                 const float* __restrict__ of, const float* __restrict__ wof,
                 const float* __restrict__ bof, float* __restrict__ offb) {
    __shared__ float lds[64][129];
    const int blk = blockIdx.x;
    const int tid = threadIdx.x;

    if (blk < 72) {                         // ---- wpack (4 sets) ----
        int t = blk * 256 + tid;
        if (t >= 4 * 4608) return;
        int set = t / 4608;
        int u   = t - set * 4608;
        const float* w = (set == 0) ? w1 : (set == 1) ? w2 : (set == 2) ? w3 : wd;
        int l  = u & 63;
        int mf = (u >> 6) & 3;
        int ch = (u >> 8) & 1;
        int kk = u >> 9;
        int co   = mf * 16 + (l & 15);
        int cin0 = ch * 32 + (l >> 4) * 8;
        half8 v;
#pragma unroll
        for (int j = 0; j < 8; ++j)
            v[j] = (_Float16)w[((co * C_) + cin0 + j) * 9 + kk];
        *(half8*)(wp + (size_t)set * 36864
                     + (size_t)(((ch * 9 + kk) * 4 + mf) * 64 + l) * 8) = v;
    } else if (blk < 121) {                 // ---- zpad of 3 arrays ----
        int t = (blk - 72) * 256 + tid;
        if (t >= 3 * B_ * 516) return;
        int which = t / (B_ * 516);
        int u = t - which * (B_ * 516);
        _Float16* o = (which == 0) ? z0 : (which == 1) ? z1 : z2;
        int b = u / 516, i = u % 516;
        int yp, xpx;
        if (i < 260) { yp = (i < 130) ? 0 : (PW - 1); xpx = i % 130; }
        else {
            int j = i - 260;
            if (j < 128) { xpx = 0; yp = j + 1; }
            else         { xpx = PW - 1; yp = j - 128 + 1; }
        }
        _Float16* dst = o + ((size_t)(b * PW + yp) * PW + xpx) * C_;
        half8 z = (half8)(_Float16)0.f;
#pragma unroll
        for (int c8 = 0; c8 < 8; ++c8) *(half8*)(dst + c8 * 8) = z;
    } else if (blk < 1145) {                // ---- xpad (NCHW->padded NHWC) ----
        int bb = blk - 121;
        const int b = bb & 7, y = bb >> 3;
        const int xr = tid & 127, cr = tid >> 7;
        const float* src = x + (size_t)b * C_ * HW_ + y * W_;
#pragma unroll
        for (int i = 0; i < 32; ++i) {
            int c = i * 2 + cr;
            lds[c][xr] = src[(size_t)c * HW_ + xr];
        }
        __syncthreads();
        const int px = tid & 127, hf = tid >> 7;
        _Float16* dst = xp + ((size_t)((b * PW + y + 1) * PW) + px + 1) * C_ + hf * 32;
#pragma unroll
        for (int q = 0; q < 4; ++q) {
            half8 v;
#pragma unroll
            for (int j = 0; j < 8; ++j) v[j] = (_Float16)lds[hf * 32 + q * 8 + j][px];
            *(half8*)(dst + q * 8) = v;
        }
    } else {                                // ---- offconv 1x1 -> [B][9][HW][2] ----
        int bb = blk - 1145;
        int bi = bb & 7;
        int p  = (bb >> 3) * 256 + tid;
        float a0 = of[(bi * 2 + 0) * HW_ + p];
        float a1 = of[(bi * 2 + 1) * HW_ + p];
#pragma unroll
        for (int kk = 0; kk < 9; ++kk) {
            float dy = bof[2 * kk]     + wof[(2 * kk) * 2] * a0     + wof[(2 * kk) * 2 + 1] * a1;
            float dx = bof[2 * kk + 1] + wof[(2 * kk + 1) * 2] * a0 + wof[(2 * kk + 1) * 2 + 1] * a1;
            float2 v; v.x = dy; v.y = dx;
            *(float2*)(offb + ((size_t)(bi * 9 + kk) * HW_ + p) * 2) = v;
        }
    }
}

// ======== conv3x3 + bias + relu: 2 rows/block, 2 blocks/CU (overlap) =======
// block = 256 thr = 4 waves (2 rows x 2 half-rows of 64px). grid 512.
// Per ch-phase: weights 36.9KB + tile 4rows x 4planes x 130 = 33.3KB -> 70.2KB
// -> 2 blocks/CU, so one block's staging overlaps the other's MFMA phase.
__global__ __launch_bounds__(256, 2)
void conv3x3_mfma(const _Float16* __restrict__ in, const _Float16* __restrict__ wpk,
                  const float* __restrict__ bias, _Float16* __restrict__ outp) {
    __shared__ _Float16 Ash[9 * 4 * 64 * 8];      // 36864 B (one ch half)
    __shared__ _Float16 Tile[4 * 4 * 130 * 8];    // 33280 B (4 rows, one ch half)
    const int tid = threadIdx.x;
    const int wv = tid >> 6, l = tid & 63;
    const int l15 = l & 15, lg = l >> 4;
    const int b  = blockIdx.x & 7;
    const int R  = (blockIdx.x >> 3) * 2;
    const int rowi = wv >> 1;
    const int xcol = (wv & 1) * 64;

    f32x4 acc[4][4];
#pragma unroll
    for (int i = 0; i < 4; ++i)
#pragma unroll
        for (int j = 0; j < 4; ++j) acc[i][j] = (f32x4){0.f, 0.f, 0.f, 0.f};

    half8 bf0[4], bf1[4];

#define LOADB(BF, KK)                                                          \
    {                                                                          \
        _Pragma("unroll") for (int nf = 0; nf < 4; ++nf)                       \
            BF[nf] = *(const half8*)(Tile + (size_t)(((rowi + (KK) / 3) * 4 + lg) \
                          * 130 + xcol + (KK) % 3 + nf * 16 + l15) * 8);       \
    }
#define MM(BF, KK)                                                             \
    {                                                                          \
        half8 af_[4];                                                          \
        _Pragma("unroll") for (int mf = 0; mf < 4; ++mf)                       \
            af_[mf] = *(const half8*)(Ash + (size_t)(((KK) * 4 + mf) * 64 + l) * 8); \
        _Pragma("unroll") for (int mf = 0; mf < 4; ++mf)                       \
            _Pragma("unroll") for (int nf = 0; nf < 4; ++nf)                   \
                acc[mf][nf] = __builtin_amdgcn_mfma_f32_16x16x32_f16(          \
                    af_[mf], BF[nf], acc[mf][nf], 0, 0, 0);                    \
    }

#pragma unroll
    for (int ch = 0; ch < 2; ++ch) {
        __syncthreads();   // previous phase's LDS readers done
        // stage weights (2304 chunks) + tile (2080 chunks) via gload_lds
#pragma unroll
        for (int i = 0; i < 18; ++i) {
            int idx = i * 256 + tid;
            if (idx < 2304) {
                stage16(wpk + (size_t)ch * 18432 + (size_t)idx * 8,
                        Ash + (size_t)idx * 8);
            } else if (idx < 4384) {
                int t   = idx - 2304;
                int dy  = t / 520;
                int rem = t - dy * 520;
                int pl  = rem / 130;
                int col = rem - pl * 130;
                stage16(in + ((size_t)((b * PW + R + dy) * PW) + col) * C_
                            + ch * 32 + pl * 8,
                        Tile + (size_t)t * 8);
            }
        }
        __syncthreads();   // drains all gload_lds

        LOADB(bf0, 0);
        LOADB(bf1, 1); MM(bf0, 0);
        LOADB(bf0, 2); MM(bf1, 1);
        LOADB(bf1, 3); MM(bf0, 2);
        LOADB(bf0, 4); MM(bf1, 3);
        LOADB(bf1, 5); MM(bf0, 4);
        LOADB(bf0, 6); MM(bf1, 5);
        LOADB(bf1, 7); MM(bf0, 6);
        LOADB(bf0, 8); MM(bf1, 7);
                       MM(bf0, 8);
    }
#undef LOADB
#undef MM

    _Float16* ob = outp + ((size_t)((b * PW + R + rowi + 1) * PW) + xcol + 1) * C_;
#pragma unroll
    for (int mf = 0; mf < 4; ++mf) {
        const int co = mf * 16 + lg * 4;
        const float b0 = bias[co], b1 = bias[co + 1], b2 = bias[co + 2], b3 = bias[co + 3];
#pragma unroll
        for (int nf = 0; nf < 4; ++nf) {
            f32x4 v = acc[mf][nf];
            half4t h;
            h[0] = (_Float16)fmaxf(v[0] + b0, 0.f);
            h[1] = (_Float16)fmaxf(v[1] + b1, 0.f);
            h[2] = (_Float16)fmaxf(v[2] + b2, 0.f);
            h[3] = (_Float16)fmaxf(v[3] + b3, 0.f);
            *(half4t*)(ob + (nf * 16 + l15) * C_ + co) = h;
        }
    }
}

// ======== deformable conv: 4 rows/block, 32px/wave (R14, unchanged) ========
__global__ __launch_bounds__(1024, 1)
void deform_mfma(const _Float16* __restrict__ hin, const float* __restrict__ off,
                 const _Float16* __restrict__ wpk, const float* __restrict__ bias,
                 float* __restrict__ out) {
    __shared__ _Float16 Ash[9 * 4 * 64 * 8];     // 36864 B (one ch half)
    __shared__ _Float16 Win[8 * 130 * 40];       // 83200 B (80B px stride)
    __shared__ _Float16 OffS[9 * 4 * 128 * 4];   // 36864 B ([tap][row][px] float2)
    const int tid = threadIdx.x;
    const int wv = tid >> 6, l = tid & 63;
    const int l15 = l & 15, lg = l >> 4;
    const int b  = blockIdx.x & 7;
    const int R  = (blockIdx.x >> 3) * 4;
    const int r  = R + (wv >> 2);
    const int xh = (wv & 3) * 32;

    const _Float16* hb = hin + (size_t)b * PW * PW * C_;
    const float* offp = off + (size_t)b * 9 * HW_ * 2;

    // stage offsets once: 9 taps x 4 rows x 128 px float2 = 2304 chunks
#pragma unroll
    for (int i = 0; i < 3; ++i) {
        int idx = i * 1024 + tid;
        if (idx < 2304) {
            int kk = idx >> 8, rowi = (idx >> 6) & 3, c = idx & 63;
            const _Float16* g = (const _Float16*)(offp
                + ((size_t)kk * HW_ + (R + rowi) * W_) * 2) + c * 8;
            stage16(g, OffS + (size_t)idx * 8);
        }
    }

    f32x4 acc[4][2];
#pragma unroll
    for (int i = 0; i < 4; ++i)
#pragma unroll
        for (int j = 0; j < 2; ++j) acc[i][j] = (f32x4){0.f, 0.f, 0.f, 0.f};

    half8 bf[2];

#define GATHB(KK, CH) do {                                                     \
    _Pragma("unroll") for (int nf = 0; nf < 2; ++nf) {                         \
        const int pxl = xh + nf * 16 + l15;                                    \
        float2 o2 = *(const float2*)(OffS +                                    \
            (size_t)((((KK) * 4 + (r - R)) << 7) + pxl) * 4);                  \
        float py = (float)(r + (KK) / 3 - 1) + o2.x;                           \
        float px = (float)(pxl + (KK) % 3 - 1) + o2.y;                         \
        float fy0 = floorf(py), fx0 = floorf(px);                              \
        float fy = py - fy0, fx = px - fx0;                                    \
        int iy0 = (int)fy0, ix0 = (int)fx0;                                    \
        int cy0 = clampi(iy0, -1, 128), cy1 = clampi(iy0 + 1, -1, 128);        \
        int px0 = clampi(ix0, -1, 128) + 1, px1 = clampi(ix0 + 1, -1, 128) + 1;\
        _Float16 w00 = (_Float16)((1.f - fy) * (1.f - fx));                    \
        _Float16 w01 = (_Float16)((1.f - fy) * fx);                            \
        _Float16 w10 = (_Float16)(fy * (1.f - fx));                            \
        _Float16 w11 = (_Float16)(fy * fx);                                    \
        half8 c0, c1, c2, c3;                                                  \
        int s0 = cy0 + 2 - R, s1 = cy1 + 2 - R;                                \
        if (__all((s0 >= 0) & (s1 <= 7))) {                                    \
            const _Float16* w0 = Win + (size_t)(s0 * 130) * 40 + lg * 8;       \
            const _Float16* w1 = Win + (size_t)(s1 * 130) * 40 + lg * 8;       \
            c0 = *(const half8*)(w0 + px0 * 40);                               \
            c1 = *(const half8*)(w0 + px1 * 40);                               \
            c2 = *(const half8*)(w1 + px0 * 40);                               \
            c3 = *(const half8*)(w1 + px1 * 40);                               \
        } else {                                                               \
            const _Float16* g0 = hb + (size_t)((cy0 + 1) * PW) * C_ + (CH) * 32 + lg * 8; \
            const _Float16* g1 = hb + (size_t)((cy1 + 1) * PW) * C_ + (CH) * 32 + lg * 8; \
            c0 = *(const half8*)(g0 + px0 * C_);                               \
            c1 = *(const half8*)(g0 + px1 * C_);                               \
            c2 = *(const half8*)(g1 + px0 * C_);                               \
            c3 = *(const half8*)(g1 + px1 * C_);                               \
        }                                                                      \
        bf[nf] = (c0 * w00 + c1 * w01) + (c2 * w10 + c3 * w11);                \
    }                                                                          \
} while (0)
#define MMT(KK) do {                                                           \
    half8 af0 = *(const half8*)(Ash + (size_t)(((KK) * 4 + 0) * 64 + l) * 8);  \
    half8 af1 = *(const half8*)(Ash + (size_t)(((KK) * 4 + 1) * 64 + l) * 8);  \
    half8 af2 = *(const half8*)(Ash + (size_t)(((KK) * 4 + 2) * 64 + l) * 8);  \
    half8 af3 = *(const half8*)(Ash + (size_t)(((KK) * 4 + 3) * 64 + l) * 8);  \
    _Pragma("unroll") for (int nf = 0; nf < 2; ++nf) {                         \
        acc[0][nf] = __builtin_amdgcn_mfma_f32_16x16x32_f16(af0, bf[nf], acc[0][nf], 0, 0, 0); \
        acc[1][nf] = __builtin_amdgcn_mfma_f32_16x16x32_f16(af1, bf[nf], acc[1][nf], 0, 0, 0); \
        acc[2][nf] = __builtin_amdgcn_mfma_f32_16x16x32_f16(af2, bf[nf], acc[2][nf], 0, 0, 0); \
        acc[3][nf] = __builtin_amdgcn_mfma_f32_16x16x32_f16(af3, bf[nf], acc[3][nf], 0, 0, 0); \
    }                                                                          \
} while (0)

#pragma unroll
    for (int ch = 0; ch < 2; ++ch) {
        __syncthreads();   // previous half's LDS readers done (drains OffS stage too)
#pragma unroll
        for (int i = 0; i < 3; ++i) {
            int idx = i * 1024 + tid;
            if (idx < 2304)
                stage16(wpk + (size_t)ch * 18432 + (size_t)idx * 8,
                        Ash + (size_t)idx * 8);
        }
#pragma unroll
        for (int i = 0; i < 6; ++i) {
            int idx = i * 1024 + tid;
            if (idx < 5200) {
                int s   = idx / 650;
                int rem = idx - s * 650;
                int c   = rem / 5;
                int q   = rem - c * 5;
                int prow = clampi(R - 1 + s, 0, 129);
                stage16(hb + ((size_t)(prow * PW) + c) * C_ + ch * 32 + (q < 4 ? q : 3) * 8,
                        Win + (size_t)idx * 8);
            }
        }
        __syncthreads();   // drains all gload_lds

        GATHB(0, ch); MMT(0);
        GATHB(1, ch); MMT(1);
        GATHB(2, ch); MMT(2);
        GATHB(3, ch); MMT(3);
        GATHB(4, ch); MMT(4);
        GATHB(5, ch); MMT(5);
        GATHB(6, ch); MMT(6);
        GATHB(7, ch); MMT(7);
        GATHB(8, ch); MMT(8);
    }
#undef GATHB
#undef MMT

    // ---- transposed epilogue: 4 passes of 16 couts through Win, full-line stores
    float* WF = (float*)Win;
    float* obase = out + (size_t)b * C_ * HW_;
#pragma unroll
    for (int p = 0; p < 4; ++p) {
        __syncthreads();   // Win free (taps done / previous pass read)
#pragma unroll
        for (int nf = 0; nf < 2; ++nf) {
            f32x4 v = acc[p][nf];
#pragma unroll
            for (int rr = 0; rr < 4; ++rr) {
                int co16 = lg * 4 + rr;
                WF[co16 * 512 + (r - R) * 128 + xh + nf * 16 + l15]
                    = v[rr] + bias[p * 16 + co16];
            }
        }
        __syncthreads();
#pragma unroll
        for (int i = 0; i < 2; ++i) {
            int g4   = i * 1024 + tid;      // f32x4 index in [0,2048)
            int co16 = g4 >> 7;             // 128 f32x4 per cout (4 rows x 128 px)
            int q    = g4 & 127;
            int rr2  = q >> 5;
            int px4  = q & 31;
            f32x4 v = *(const f32x4*)&WF[g4 * 4];
            *(f32x4*)(obase + (size_t)(p * 16 + co16) * HW_ + (R + rr2) * W_ + px4 * 4) = v;
        }
    }
}

extern "C" void kernel_launch(void* const* d_in, const int* in_sizes, int n_in,
                              void* d_out, int out_size, void* d_ws, size_t ws_size,
                              hipStream_t stream) {
    const float* x     = (const float*)d_in[0];
    const float* of    = (const float*)d_in[1];
    const float* w1    = (const float*)d_in[2];
    const float* b1    = (const float*)d_in[3];
    const float* w2    = (const float*)d_in[4];
    const float* b2    = (const float*)d_in[5];
    const float* w3    = (const float*)d_in[6];
    const float* b3    = (const float*)d_in[7];
    const float* w_off = (const float*)d_in[8];
    const float* b_off = (const float*)d_in[9];
    const float* w_d   = (const float*)d_in[10];
    const float* b_d   = (const float*)d_in[11];
    float* out = (float*)d_out;

    char* base = (char*)d_ws;
    float*     offb = (float*)base;                           // 9.44 MB
    char* p = base + (size_t)B_ * 18 * HW_ * 4;
    _Float16* wpA = (_Float16*)p;                             // 4 contiguous sets
    _Float16* wp1 = wpA;
    _Float16* wp2 = wp1 + 36864;
    _Float16* wp3 = wp2 + 36864;
    _Float16* wpd = wp3 + 36864;
    p += 4 * 36864 * 2;
    _Float16* xp = (_Float16*)p; p += (size_t)B_ * PW * PW * C_ * 2;  // 17.3 MB
    _Float16* hA = (_Float16*)p; p += (size_t)B_ * PW * PW * C_ * 2;
    _Float16* hB = (_Float16*)p;

    prep_kernel<<<1657, 256, 0, stream>>>(w1, w2, w3, w_d, wpA,
                                          xp, hA, hB,
                                          x, xp, of, w_off, b_off, offb);

    conv3x3_mfma<<<512, 256, 0, stream>>>(xp, wp1, b1, hA);
    conv3x3_mfma<<<512, 256, 0, stream>>>(hA, wp2, b2, hB);
    conv3x3_mfma<<<512, 256, 0, stream>>>(hB, wp3, b3, hA);
    deform_mfma<<<256, 1024, 0, stream>>>(hA, offb, wpd, b_d, out);
}